// Round 3
// baseline (795.749 us; speedup 1.0000x reference)
//
#include <hip/hip_runtime.h>

// GNN_layer: N=4, A_IN=8, A_OUT=16, X=64, n=1024.
// Inputs: float32. Outputs: float32 (reference output dtype).
// Decomposition:
//   At[b,i,j,s] = Base + pairA[i,s] + pairA[j,s] + constA[s],  Base = sum_c A[b,c,i,j] W1[c,s]
//   einsum factors through G[b,c,i,t] = A[b,c] @ X2t (MFMA, A cast to bf16 in-reg),
//   so the 268 MB At output is written once and never re-read.

#define NB 4
#define CI 8
#define SO 16
#define XD 64
#define NN 1024

typedef unsigned short u16;
typedef unsigned int u32;
typedef float f32x4 __attribute__((ext_vector_type(4)));
typedef short bf16x8 __attribute__((ext_vector_type(8)));

// ---- workspace layout (bytes), total 0x660000 = 6.7 MB ----
#define WS_MOC    0x000000u  // f32[4*8*1024]
#define WS_DP     0x020000u  // f32[4*8*1024]
#define WS_CONSTA 0x043000u  // f32[4*16]
#define WS_CX1    0x044000u  // f32[4*64]
#define WS_CX2    0x045000u  // f32[4*64]
#define WS_K1     0x048000u  // f32[4*16*64]
#define WS_C2     0x04C000u  // f32[4*64]
#define WS_PAIRA  0x050000u  // f32[4*1024*16]
#define WS_PAIRAT 0x090000u  // f32[4*16*1024]
#define WS_X1T    0x0D0000u  // f32[4*1024*64]
#define WS_X2TT   0x1D0000u  // bf16[4*64*1024]
#define WS_WGT    0x250000u  // bf16[64*512]
#define WS_G      0x260000u  // bf16[4*8*1024*64]

__device__ __forceinline__ float bf2f(u16 u){ return __uint_as_float(((u32)u) << 16); }
__device__ __forceinline__ u16 f2bf(float f){
    u32 x = __float_as_uint(f);
    x += 0x7fffu + ((x >> 16) & 1u);
    return (u16)(x >> 16);
}

// ---------------- K1: per-row stats of A: moc (row mean) and dp (diag) ----------------
__global__ __launch_bounds__(256) void k_rowstats(const float* __restrict__ A,
                                                  float* __restrict__ moc,
                                                  float* __restrict__ dpv)
{
    int wave = threadIdx.x >> 6, lane = threadIdx.x & 63;
    int row = blockIdx.x * 4 + wave;           // (b*8+c)*1024 + i
    int i = row & (NN - 1);
    const float* rp = A + (size_t)row * NN;
    f32x4 v0 = *(const f32x4*)(rp + lane * 16);
    f32x4 v1 = *(const f32x4*)(rp + lane * 16 + 4);
    f32x4 v2 = *(const f32x4*)(rp + lane * 16 + 8);
    f32x4 v3 = *(const f32x4*)(rp + lane * 16 + 12);
    float s = 0.f;
    #pragma unroll
    for (int e = 0; e < 4; e++) s += v0[e] + v1[e] + v2[e] + v3[e];
    #pragma unroll
    for (int off = 32; off; off >>= 1) s += __shfl_down(s, off);
    if (lane == 0) {
        moc[row] = s * (1.f / NN);
        dpv[row] = rp[i];
    }
}

// ---------------- K2: per-batch constants ----------------
__global__ __launch_bounds__(256) void k_batchstats(const float* __restrict__ X,
    const float* __restrict__ moc, const float* __restrict__ dpv,
    const float* __restrict__ AW2, const float* __restrict__ AW4, const float* __restrict__ AW7,
    const float* __restrict__ Abias,
    const float* __restrict__ X1W2, const float* __restrict__ X1W5, const float* __restrict__ X1W6,
    const float* __restrict__ X1b,
    const float* __restrict__ X2W2, const float* __restrict__ X2W5, const float* __restrict__ X2W6,
    const float* __restrict__ X2b,
    float* __restrict__ constA_o, float* __restrict__ cx1_o, float* __restrict__ cx2_o)
{
    int b = blockIdx.x, tid = threadIdx.x;
    __shared__ float sdp[8][32], smoc[8][32], smx[4][64];
    __shared__ float mdp_s[8], mall_s[8], mx_s[64];
    {
        int c = tid >> 5, rr = tid & 31;
        float pd = 0.f, pm = 0.f;
        for (int i = rr; i < NN; i += 32) {
            pd += dpv[(b*CI + c)*NN + i];
            pm += moc[(b*CI + c)*NN + i];
        }
        sdp[c][rr] = pd; smoc[c][rr] = pm;
    }
    {
        int x = tid & 63, g = tid >> 6;
        float px = 0.f;
        for (int i = g; i < NN; i += 4) px += X[((size_t)b*NN + i)*XD + x];
        smx[g][x] = px;
    }
    __syncthreads();
    if (tid < 8) {
        float sd = 0.f, sm = 0.f;
        for (int k = 0; k < 32; k++) { sd += sdp[tid][k]; sm += smoc[tid][k]; }
        mdp_s[tid] = sd * (1.f/NN); mall_s[tid] = sm * (1.f/NN);
    }
    if (tid < 64) mx_s[tid] = (smx[0][tid]+smx[1][tid]+smx[2][tid]+smx[3][tid]) * (1.f/NN);
    __syncthreads();
    if (tid < SO) {
        float v = Abias[tid];
        #pragma unroll
        for (int c = 0; c < 8; c++)
            v += mall_s[c]*AW2[c*SO+tid] + mdp_s[c]*AW4[c*SO+tid];
        for (int x = 0; x < 64; x++) v += mx_s[x]*AW7[x*SO+tid];
        constA_o[b*SO + tid] = v;
    }
    if (tid < 64) {
        float v1 = X1b[tid], v2 = X2b[tid];
        for (int x = 0; x < 64; x++) {
            float m = mx_s[x];
            v1 += m*X1W2[x*64+tid];
            v2 += m*X2W2[x*64+tid];
        }
        #pragma unroll
        for (int c = 0; c < 8; c++) {
            v1 += mall_s[c]*X1W6[c*64+tid] + mdp_s[c]*X1W5[c*64+tid];
            v2 += mall_s[c]*X2W6[c*64+tid] + mdp_s[c]*X2W5[c*64+tid];
        }
        cx1_o[b*64+tid] = v1; cx2_o[b*64+tid] = v2;
    }
}

// ---------------- K3: per-node row quantities: pairA, X1t, X2t^T ----------------
__global__ __launch_bounds__(256) void k_rows(const float* __restrict__ X,
    const float* __restrict__ moc, const float* __restrict__ dpv,
    const float* __restrict__ AW3, const float* __restrict__ AW5, const float* __restrict__ AW6,
    const float* __restrict__ X1W1, const float* __restrict__ X1W3, const float* __restrict__ X1W4,
    const float* __restrict__ X2W1, const float* __restrict__ X2W3, const float* __restrict__ X2W4,
    const float* __restrict__ cx1, const float* __restrict__ cx2,
    float* __restrict__ X1t, u16* __restrict__ X2tT,
    float* __restrict__ pairA, float* __restrict__ pairAT)
{
    int wave = threadIdx.x >> 6, u = threadIdx.x & 63;
    int r = blockIdx.x * 4 + wave;
    int b = r >> 10, i = r & (NN - 1);
    float xv = X[(size_t)r*XD + u];
    float a1 = cx1[b*XD + u], a2 = cx2[b*XD + u];
    int s = u & 15;
    float pa = 0.f;
    for (int x = 0; x < XD; x++) {
        float xx = __shfl(xv, x);
        a1 += xx * X1W1[x*XD + u];
        a2 += xx * X2W1[x*XD + u];
        pa += xx * AW6[x*SO + s];
    }
    #pragma unroll
    for (int c = 0; c < CI; c++) {
        float mv = moc[(b*CI + c)*NN + i];
        float dv = dpv[(b*CI + c)*NN + i];
        a1 += mv*X1W3[c*XD+u] + dv*X1W4[c*XD+u];
        a2 += mv*X2W3[c*XD+u] + dv*X2W4[c*XD+u];
        pa += mv*AW3[c*SO+s] + dv*AW5[c*SO+s];
    }
    X1t[(size_t)r*XD + u] = a1;
    X2tT[((size_t)b*XD + u)*NN + i] = f2bf(a2);
    if (u < SO) {
        pairA[(size_t)r*SO + u] = pa;
        pairAT[((size_t)b*SO + u)*NN + i] = pa;
    }
}

// ---------------- K4: small per-batch reductions + fused weights ----------------
__global__ __launch_bounds__(256) void k_small(const float* __restrict__ Wo, const float* __restrict__ AW1,
    const float* __restrict__ constA, const float* __restrict__ pairAT, const u16* __restrict__ X2tT,
    float* __restrict__ K1, float* __restrict__ C2, u16* __restrict__ WGT)
{
    int tid = threadIdx.x;
    if (blockIdx.x < 4) {
        int b = blockIdx.x;
        __shared__ float ls[4][64];
        __shared__ float s2sh[64];
        __shared__ float Hsh[16][64];
        int t = tid & 63, g = tid >> 6;
        float p = 0.f;
        for (int i = g; i < NN; i += 4) p += bf2f(X2tT[((size_t)b*XD + t)*NN + i]);
        ls[g][t] = p;
        __syncthreads();
        if (tid < 64) s2sh[tid] = ls[0][tid]+ls[1][tid]+ls[2][tid]+ls[3][tid];
        __syncthreads();
        {
            const u16* x2 = X2tT + ((size_t)b*XD + t)*NN;
            for (int p4 = 0; p4 < 4; p4++) {
                int s = p4*4 + g;
                const float* par = pairAT + ((size_t)b*SO + s)*NN;
                float h = 0.f;
                for (int i = 0; i < NN; i++) h += par[i] * bf2f(x2[i]);
                Hsh[s][t] = h;
            }
        }
        __syncthreads();
        for (int p4 = 0; p4 < 4; p4++) {
            int s = p4*4 + g;
            float v = 0.f;
            for (int tt = 0; tt < 64; tt++) v += s2sh[tt] * Wo[(s*64+tt)*64 + t];
            K1[((size_t)b*SO + s)*XD + t] = v;
        }
        float pc = 0.f;
        for (int s = g*4; s < g*4 + 4; s++) {
            float ca = constA[b*SO + s];
            for (int tt = 0; tt < 64; tt++)
                pc += (Hsh[s][tt] + ca*s2sh[tt]) * Wo[(s*64+tt)*64 + t];
        }
        __syncthreads();
        ls[g][t] = pc;
        __syncthreads();
        if (tid < 64) C2[b*XD + tid] = (ls[0][tid]+ls[1][tid]+ls[2][tid]+ls[3][tid]) * (1.f/NN);
    } else {
        int u0 = (blockIdx.x - 4) * 16;
        for (int q = 0; q < 32; q++) {
            int o = q*256 + tid;
            int u = u0 + (o >> 9);
            int k = o & 511;
            int c = k >> 6, t = k & 63;
            float v = 0.f;
            #pragma unroll
            for (int s = 0; s < SO; s++) v += AW1[c*SO+s] * Wo[(s*64+t)*64 + u];
            WGT[(size_t)u*512 + k] = f2bf(v);
        }
    }
}

// ---------------- K5: At writer (output 0, fp32, layout [b,s,i,j]) ----------------
__global__ __launch_bounds__(256) void k_At(const float* __restrict__ A, const float* __restrict__ AW1,
    const float* __restrict__ pairA, const float* __restrict__ pairAT,
    const float* __restrict__ constA, float* __restrict__ out0)
{
    __shared__ float W1s[CI][SO];
    __shared__ float rc[4][SO];
    int tid = threadIdx.x, wave = tid >> 6, lane = tid & 63;
    int r = blockIdx.x * 4 + wave;
    int b = r >> 10, i = r & (NN - 1);
    if (tid < CI*SO) W1s[tid >> 4][tid & 15] = AW1[tid];
    if (lane < SO) rc[wave][lane] = pairA[(size_t)r*SO + lane] + constA[b*SO + lane];
    __syncthreads();
    const float* Ab = A + ((size_t)b*CI)*NN*NN + (size_t)i*NN;
    for (int jc = 0; jc < NN; jc += 512) {
        int j0 = jc + lane*8;
        float av[CI][8];
        #pragma unroll
        for (int c = 0; c < CI; c++) {
            f32x4 a0 = *(const f32x4*)(Ab + (size_t)c*NN*NN + j0);
            f32x4 a1 = *(const f32x4*)(Ab + (size_t)c*NN*NN + j0 + 4);
            #pragma unroll
            for (int e = 0; e < 4; e++) { av[c][e] = a0[e]; av[c][e+4] = a1[e]; }
        }
        #pragma unroll
        for (int s = 0; s < SO; s++) {
            const float* pt = pairAT + ((size_t)b*SO + s)*NN + j0;
            f32x4 p0 = *(const f32x4*)pt;
            f32x4 p1 = *(const f32x4*)(pt + 4);
            float base = rc[wave][s];
            f32x4 o0, o1;
            #pragma unroll
            for (int e = 0; e < 4; e++) { o0[e] = base + p0[e]; o1[e] = base + p1[e]; }
            #pragma unroll
            for (int c = 0; c < CI; c++) {
                float wv = W1s[c][s];
                #pragma unroll
                for (int e = 0; e < 4; e++) { o0[e] += av[c][e] * wv; o1[e] += av[c][e+4] * wv; }
            }
            float* op = out0 + (((size_t)(b*SO + s))*NN + i)*NN + j0;
            *(f32x4*)op = o0;
            *(f32x4*)(op + 4) = o1;
        }
    }
}

// ---------------- K6: G[b,c] = A[b,c] @ X2t  (MFMA 16x16x32 bf16) ----------------
__global__ __launch_bounds__(256) void k_G(const float* __restrict__ A, const u16* __restrict__ X2tT,
                                           u16* __restrict__ G)
{
    int tid = threadIdx.x, wave = tid >> 6, lane = tid & 63;
    int lr = lane & 15, lq = lane >> 4;
    int bc = blockIdx.x >> 3;
    int b = bc >> 3;
    int m_base = (blockIdx.x & 7)*128 + wave*32;
    const float* Ab = A + (size_t)bc*NN*NN;
    const u16* Xb = X2tT + (size_t)b*XD*NN;
    f32x4 acc[2][4];
    #pragma unroll
    for (int mt = 0; mt < 2; mt++)
        #pragma unroll
        for (int nt = 0; nt < 4; nt++) acc[mt][nt] = (f32x4){0.f, 0.f, 0.f, 0.f};
    for (int k0 = 0; k0 < NN; k0 += 32) {
        bf16x8 af[2], bfr[4];
        #pragma unroll
        for (int mt = 0; mt < 2; mt++) {
            const float* ar = Ab + (size_t)(m_base + mt*16 + lr)*NN + k0 + lq*8;
            f32x4 x0 = *(const f32x4*)ar;
            f32x4 x1 = *(const f32x4*)(ar + 4);
            bf16x8 t;
            #pragma unroll
            for (int e = 0; e < 4; e++) { t[e] = (short)f2bf(x0[e]); t[e+4] = (short)f2bf(x1[e]); }
            af[mt] = t;
        }
        #pragma unroll
        for (int nt = 0; nt < 4; nt++)
            bfr[nt] = __builtin_bit_cast(bf16x8,
                *(const uint4*)(Xb + (size_t)(nt*16 + lr)*NN + k0 + lq*8));
        #pragma unroll
        for (int mt = 0; mt < 2; mt++)
            #pragma unroll
            for (int nt = 0; nt < 4; nt++)
                acc[mt][nt] = __builtin_amdgcn_mfma_f32_16x16x32_bf16(af[mt], bfr[nt], acc[mt][nt], 0, 0, 0);
    }
    #pragma unroll
    for (int mt = 0; mt < 2; mt++)
        #pragma unroll
        for (int nt = 0; nt < 4; nt++)
            #pragma unroll
            for (int reg = 0; reg < 4; reg++) {
                int ii = m_base + mt*16 + lq*4 + reg;
                int t  = nt*16 + lr;
                G[((size_t)bc*NN + ii)*XD + t] = f2bf(acc[mt][nt][reg]);
            }
}

// ---------------- K7: out1[b,i,u] = (1/n)(G.WG + pairA.K1) + C2 + ob + X1t (fp32) ----------------
__global__ __launch_bounds__(256) void k_out(const u16* __restrict__ G, const u16* __restrict__ WGT,
    const float* __restrict__ pairA, const float* __restrict__ K1, const float* __restrict__ C2,
    const float* __restrict__ X1t, const float* __restrict__ outb, float* __restrict__ out1)
{
    int tid = threadIdx.x, wave = tid >> 6, lane = tid & 63;
    int lr = lane & 15, lq = lane >> 4;
    int rbase = blockIdx.x*128 + wave*32;
    int b = rbase >> 10;
    int ib = rbase & (NN - 1);
    f32x4 acc[2][4];
    #pragma unroll
    for (int mt = 0; mt < 2; mt++)
        #pragma unroll
        for (int nt = 0; nt < 4; nt++) acc[mt][nt] = (f32x4){0.f, 0.f, 0.f, 0.f};
    for (int k0 = 0; k0 < 512; k0 += 32) {
        int c = k0 >> 6;
        int tp = (k0 & 63) + lq*8;
        bf16x8 af[2], bfr[4];
        #pragma unroll
        for (int mt = 0; mt < 2; mt++) {
            size_t grow = (size_t)(b*CI + c)*NN + ib + mt*16 + lr;
            af[mt] = __builtin_bit_cast(bf16x8, *(const uint4*)(G + grow*XD + tp));
        }
        #pragma unroll
        for (int nt = 0; nt < 4; nt++)
            bfr[nt] = __builtin_bit_cast(bf16x8,
                *(const uint4*)(WGT + (size_t)(nt*16 + lr)*512 + k0 + lq*8));
        #pragma unroll
        for (int mt = 0; mt < 2; mt++)
            #pragma unroll
            for (int nt = 0; nt < 4; nt++)
                acc[mt][nt] = __builtin_amdgcn_mfma_f32_16x16x32_bf16(af[mt], bfr[nt], acc[mt][nt], 0, 0, 0);
    }
    float k1c[4][SO];
    #pragma unroll
    for (int nt = 0; nt < 4; nt++) {
        int u = nt*16 + lr;
        #pragma unroll
        for (int s = 0; s < SO; s++) k1c[nt][s] = K1[((size_t)b*SO + s)*XD + u];
    }
    #pragma unroll
    for (int mt = 0; mt < 2; mt++)
        #pragma unroll
        for (int reg = 0; reg < 4; reg++) {
            int ii = ib + mt*16 + lq*4 + reg;
            const float* pa = pairA + ((size_t)b*NN + ii)*SO;
            float pav[SO];
            #pragma unroll
            for (int s = 0; s < SO; s++) pav[s] = pa[s];
            #pragma unroll
            for (int nt = 0; nt < 4; nt++) {
                int u = nt*16 + lr;
                float s16 = 0.f;
                #pragma unroll
                for (int s = 0; s < SO; s++) s16 += pav[s] * k1c[nt][s];
                float val = (acc[mt][nt][reg] + s16) * (1.f/NN)
                          + C2[b*XD + u] + outb[u]
                          + X1t[((size_t)b*NN + ii)*XD + u];
                out1[((size_t)b*NN + ii)*XD + u] = val;
            }
        }
}

extern "C" void kernel_launch(void* const* d_in, const int* in_sizes, int n_in,
                              void* d_out, int out_size, void* d_ws, size_t ws_size,
                              hipStream_t stream)
{
    const float* A     = (const float*)d_in[0];
    const float* X     = (const float*)d_in[1];
    const float* AW1   = (const float*)d_in[2];
    const float* AW2   = (const float*)d_in[3];
    const float* AW3   = (const float*)d_in[4];
    const float* AW4   = (const float*)d_in[5];
    const float* AW5   = (const float*)d_in[6];
    const float* AW6   = (const float*)d_in[7];
    const float* AW7   = (const float*)d_in[8];
    const float* Abias = (const float*)d_in[9];
    const float* X1W1  = (const float*)d_in[10];
    const float* X1W2  = (const float*)d_in[11];
    const float* X1W3  = (const float*)d_in[12];
    const float* X1W4  = (const float*)d_in[13];
    const float* X1W5  = (const float*)d_in[14];
    const float* X1W6  = (const float*)d_in[15];
    const float* X1b   = (const float*)d_in[16];
    const float* X2W1  = (const float*)d_in[17];
    const float* X2W2  = (const float*)d_in[18];
    const float* X2W3  = (const float*)d_in[19];
    const float* X2W4  = (const float*)d_in[20];
    const float* X2W5  = (const float*)d_in[21];
    const float* X2W6  = (const float*)d_in[22];
    const float* X2b   = (const float*)d_in[23];
    const float* Wo    = (const float*)d_in[24];
    const float* outb  = (const float*)d_in[25];

    char* ws = (char*)d_ws;
    float* moc    = (float*)(ws + WS_MOC);
    float* dpv    = (float*)(ws + WS_DP);
    float* constA = (float*)(ws + WS_CONSTA);
    float* cx1    = (float*)(ws + WS_CX1);
    float* cx2    = (float*)(ws + WS_CX2);
    float* K1     = (float*)(ws + WS_K1);
    float* C2     = (float*)(ws + WS_C2);
    float* pairA  = (float*)(ws + WS_PAIRA);
    float* pairAT = (float*)(ws + WS_PAIRAT);
    float* X1t    = (float*)(ws + WS_X1T);
    u16*   X2tT   = (u16*)(ws + WS_X2TT);
    u16*   WGT    = (u16*)(ws + WS_WGT);
    u16*   G      = (u16*)(ws + WS_G);

    float* out0 = (float*)d_out;
    float* out1 = out0 + (size_t)NB*SO*NN*NN;

    k_rowstats<<<dim3(NB*CI*NN/4), dim3(256), 0, stream>>>(A, moc, dpv);
    k_batchstats<<<dim3(NB), dim3(256), 0, stream>>>(X, moc, dpv,
        AW2, AW4, AW7, Abias, X1W2, X1W5, X1W6, X1b, X2W2, X2W5, X2W6, X2b,
        constA, cx1, cx2);
    k_rows<<<dim3(NB*NN/4), dim3(256), 0, stream>>>(X, moc, dpv,
        AW3, AW5, AW6, X1W1, X1W3, X1W4, X2W1, X2W3, X2W4, cx1, cx2,
        X1t, X2tT, pairA, pairAT);
    k_small<<<dim3(8), dim3(256), 0, stream>>>(Wo, AW1, constA, pairAT, X2tT, K1, C2, WGT);
    k_G<<<dim3(NB*CI*8), dim3(256), 0, stream>>>(A, X2tT, G);
    k_At<<<dim3(NB*NN/4), dim3(256), 0, stream>>>(A, AW1, pairA, pairAT, constA, out0);
    k_out<<<dim3(NB*NN/128), dim3(256), 0, stream>>>(G, WGT, pairA, K1, C2, X1t, outb, out1);
}